// Round 7
// baseline (155.858 us; speedup 1.0000x reference)
//
#include <hip/hip_runtime.h>
#include <hip/hip_bf16.h>
#include <math.h>

// Sizes
#define HH 4
#define BB 8
#define CC 64
#define RR 64
#define LL 2048
#define AA 8
#define HC 256   // H*C
#define EPS 1e-5f
#define CHP 266  // conv1 LDS row pad: 133 dwords/row, 5i bank walk

typedef unsigned short ushort_t;
typedef __attribute__((ext_vector_type(8))) short short8;
typedef __attribute__((ext_vector_type(4))) float f32x4;

static __device__ __forceinline__ ushort_t f2bf(float x) {
    unsigned u = __float_as_uint(x);
    unsigned r = (u + 0x7FFF + ((u >> 16) & 1)) >> 16;
    return (ushort_t)r;
}
static __device__ __forceinline__ float bf2f(ushort_t h) {
    return __uint_as_float(((unsigned)h) << 16);
}

// ---------------------------------------------------------------------------
// Kernel A: fused K/V GEMM (+ weight-prep partition at blockIdx.x==32).
// GEMM: out rows 0..63 = K = key_w[h] @ inputs[h,b], rows 64..127 = V.
// grid (33, 32), block 256 (4 waves).
__global__ __launch_bounds__(256) void kA(const float* __restrict__ inp,
                                          const float* __restrict__ kw,
                                          const float* __restrict__ vw,
                                          float* __restrict__ K,
                                          float* __restrict__ V,
                                          const float* __restrict__ pw1,
                                          const float* __restrict__ g1,
                                          const float* __restrict__ m1,
                                          const float* __restrict__ v1,
                                          const float* __restrict__ bb1,
                                          const float* __restrict__ pw2,
                                          const float* __restrict__ g2,
                                          const float* __restrict__ m2,
                                          const float* __restrict__ v2,
                                          const float* __restrict__ bb2,
                                          const float* __restrict__ w1ca,
                                          ushort_t* __restrict__ wEb,
                                          ushort_t* __restrict__ wFb,
                                          float* __restrict__ biasE,
                                          float* __restrict__ biasF,
                                          float* __restrict__ w1T) {
    if (blockIdx.x == 32) {
        // ---- weight prep partition: 32 blocks x 256 thr = 8192 threads ----
        int tid = blockIdx.y * 256 + threadIdx.x;
        const int stride = 32 * 256;
        // conv1 A-frag bf16 pack: r = rg*16+(lane&15), k = ks*32+(lane>>4)*8+j,
        // k tap-major: tap = k>>8, ch = k&255
        for (int idx = tid; idx < 4 * 24 * 64 * 8; idx += stride) {
            int j = idx & 7, lane = (idx >> 3) & 63, t2 = idx >> 9;
            int ks = t2 % 24, rg = t2 / 24;
            int r = rg * 16 + (lane & 15);
            int k = ks * 32 + (lane >> 4) * 8 + j;
            int tap = k >> 8, ch = k & 255;
            float inv = g1[r] * rsqrtf(v1[r] + EPS);
            wEb[idx] = f2bf(pw1[(r * 256 + ch) * 3 + tap] * inv);
        }
        // conv2 A-frag bf16 pack: K=192, tap = k>>6, c = k&63
        for (int idx = tid; idx < 4 * 6 * 64 * 8; idx += stride) {
            int j = idx & 7, lane = (idx >> 3) & 63, t2 = idx >> 9;
            int ks = t2 % 6, rg = t2 / 6;
            int r = rg * 16 + (lane & 15);
            int k = ks * 32 + (lane >> 4) * 8 + j;
            int tap = k >> 6, c = k & 63;
            float inv = g2[r] * rsqrtf(v2[r] + EPS);
            wFb[idx] = f2bf(pw2[(r * 64 + c) * 3 + tap] * inv);
        }
        for (int idx = tid; idx < 320 * 8; idx += stride)
            w1T[idx] = w1ca[(idx & 7) * 320 + (idx >> 3)];
        if (tid < 64) {
            float inv1 = g1[tid] * rsqrtf(v1[tid] + EPS);
            biasE[tid] = bb1[tid] - m1[tid] * inv1;
            float inv2 = g2[tid] * rsqrtf(v2[tid] + EPS);
            biasF[tid] = bb2[tid] - m2[tid] * inv2;
        }
        return;
    }
    int hb = blockIdx.x;
    int h = hb >> 3;
    int l0 = blockIdx.y * 64;
    __shared__ float in_s[64][64];
    __shared__ float wT[64][128];   // [c][row]; row<64: key, row>=64: value
    int t = threadIdx.x;
    const float* kwh = kw + h * 4096;
    const float* vwh = vw + h * 4096;
    for (int idx = t; idx < 4096; idx += 256) {
        int r = idx >> 6, c = idx & 63;
        wT[c][r] = kwh[idx];        // kwh[r*64+c]
        wT[c][64 + r] = vwh[idx];
    }
    for (int idx = t; idx < 4096; idx += 256) {
        int c = idx >> 6, j = idx & 63;
        in_s[c][j] = inp[(size_t)(hb * 64 + c) * LL + l0 + j];
    }
    __syncthreads();
    int w = t >> 6, lane = t & 63;
    int mg = lane & 15, rg = lane >> 4;
    int rowbase = w * 32 + rg * 8;
    int jx = mg * 4;
    float acc[8][4] = {};
    for (int c = 0; c < 64; ++c) {
        float4 x = *(const float4*)&in_s[c][jx];
        float4 wa = *(const float4*)&wT[c][rowbase];
        float4 wb = *(const float4*)&wT[c][rowbase + 4];
        float wv[8] = {wa.x, wa.y, wa.z, wa.w, wb.x, wb.y, wb.z, wb.w};
        float xv[4] = {x.x, x.y, x.z, x.w};
#pragma unroll
        for (int i = 0; i < 8; ++i)
#pragma unroll
            for (int k = 0; k < 4; ++k)
                acc[i][k] += wv[i] * xv[k];
    }
#pragma unroll
    for (int i = 0; i < 8; ++i) {
        int row = rowbase + i;
        float* dst = (row < 64 ? K : V);
        float4 o = {acc[i][0], acc[i][1], acc[i][2], acc[i][3]};
        *(float4*)&dst[(size_t)(hb * 64 + (row & 63)) * LL + l0 + jx] = o;
    }
}

// ---------------------------------------------------------------------------
// Kernel BC: banded softmax stats (u, w[5]) + S-partials for its l-chunk.
// grid (H*B, LL/128), block 128.
__global__ __launch_bounds__(128) void kBC(const float* __restrict__ K,
                                           const float* __restrict__ V,
                                           const float* __restrict__ hidden,
                                           float* __restrict__ U,
                                           float* __restrict__ W,
                                           float* __restrict__ Spart) {
    int hb = blockIdx.x;
    int b = hb & 7;
    int l0 = blockIdx.y * 128;
    __shared__ float k_s[64][132];
    __shared__ float red[64][2];
    const float* Kb = K + (size_t)(hb * 64) * LL;
    int t = threadIdx.x;
    for (int idx = t; idx < 64 * 132; idx += 128) {
        int r = idx / 132, j = idx % 132;
        int m = l0 - 2 + j;
        k_s[r][j] = (m >= 0 && m < LL) ? Kb[(size_t)r * LL + m] : 0.f;
    }
    __syncthreads();
    int l = l0 + t;
    float acc[5] = {};
    const float* hbp = hidden + (size_t)(b * 64) * LL + l0 + t;
    for (int r = 0; r < 64; ++r) {
        float h = hbp[(size_t)r * LL];
        acc[0] += h * k_s[r][t];
        acc[1] += h * k_s[r][t + 1];
        acc[2] += h * k_s[r][t + 2];
        acc[3] += h * k_s[r][t + 3];
        acc[4] += h * k_s[r][t + 4];
    }
    float raw[5];
    float mx = 0.f;
    int nv = 0;
#pragma unroll
    for (int d = 0; d < 5; ++d) {
        int m = l + d - 2;
        bool valid = (m >= 0 && m < LL);
        raw[d] = valid ? acc[d] * 0.125f : -1e30f;
        if (valid) { nv++; mx = fmaxf(mx, raw[d]); }
    }
    float e0 = __expf(-mx);
    float Z = (float)(LL - nv) * e0;
    float w[5];
#pragma unroll
    for (int d = 0; d < 5; ++d) {
        float e = (raw[d] > -1e29f) ? __expf(raw[d] - mx) : 0.f;
        w[d] = e;
        Z += e;
    }
    float inv = 1.f / Z;
    float u = e0 * inv;
    U[(size_t)hb * LL + l] = u;
#pragma unroll
    for (int d = 0; d < 5; ++d) W[((size_t)hb * LL + l) * 5 + d] = w[d] * inv;
    // ---- S partial phase: Spart[hb][q][c] = sum_{l in chunk} V[c][l]*u[l] ----
    const float* Vb = V + (size_t)(hb * 64) * LL + l0 + t;
    int wv = t >> 6;
    for (int c = 0; c < 64; ++c) {
        float prod = Vb[(size_t)c * LL] * u;
#pragma unroll
        for (int off = 32; off; off >>= 1) prod += __shfl_down(prod, off);
        if ((t & 63) == 0) red[c][wv] = prod;
    }
    __syncthreads();
    if (t < 64)
        Spart[((size_t)hb * 16 + blockIdx.y) * 64 + t] = red[t][0] + red[t][1];
}

// ---------------------------------------------------------------------------
// Kernel D: val + residual -> x (registers); channel attention -> gate; write XG
// grid (B, L/64), block 512 (8 waves). lane = m; wave wv owns c = wv*8..+8 per head.
__global__ __launch_bounds__(512) void kD(const float* __restrict__ inp,
                                          const float* __restrict__ hidden,
                                          const float* __restrict__ V,
                                          const float* __restrict__ U,
                                          const float* __restrict__ W,
                                          const float* __restrict__ Spart,
                                          const float* __restrict__ w1T,
                                          const float* __restrict__ b1,
                                          const float* __restrict__ w2,
                                          const float* __restrict__ b2,
                                          float* __restrict__ XG) {
    int b = blockIdx.x;
    int m0 = blockIdx.y * 64;
    __shared__ float Vt[64][68];        // one head's V tile, halo 2 (17.4KB)
    __shared__ float dw_s[4][68][5];    // (w - u) per head/row (5.4KB)
    __shared__ float S_s[256];          // 1KB
    __shared__ float partial[8][64][9]; // padded (18.4KB)
    int t = threadIdx.x;
    int m = t & 63;
    int wv = t >> 6;
    // --- phase 0 staging ---
    for (int idx = t; idx < 4 * 68; idx += 512) {
        int h = idx / 68, j = idx % 68;
        int l = m0 - 2 + j;
        int hb = h * 8 + b;
        if (l >= 0 && l < LL) {
            float u = U[(size_t)hb * LL + l];
            const float* wp = &W[((size_t)hb * LL + l) * 5];
#pragma unroll
            for (int d = 0; d < 5; ++d) dw_s[h][j][d] = wp[d] - u;
        } else {
#pragma unroll
            for (int d = 0; d < 5; ++d) dw_s[h][j][d] = 0.f;
        }
    }
    if (t < 256) {
        float s = 0.f;
        int hb = (t >> 6) * 8 + b;
#pragma unroll
        for (int q = 0; q < 16; ++q) s += Spart[((size_t)hb * 16 + q) * 64 + (t & 63)];
        S_s[t] = s;
    }
    // --- phase 1: x = inputs + S + banded correction; x kept in registers ---
    float xr[4][8];
#pragma unroll
    for (int h = 0; h < 4; ++h) {
        __syncthreads();   // Vt reusable / staging done (h==0)
        int hb8 = h * 8 + b;
        for (int idx = t; idx < 64 * 68; idx += 512) {
            int c = idx / 68, j = idx % 68;
            int l = m0 - 2 + j;
            Vt[c][j] = (l >= 0 && l < LL) ? V[(size_t)(hb8 * 64 + c) * LL + l] : 0.f;
        }
        __syncthreads();   // Vt ready
        float dwv[5];
#pragma unroll
        for (int d = 0; d < 5; ++d) dwv[d] = dw_s[h][m + 4 - d][d];
#pragma unroll
        for (int cc = 0; cc < 8; ++cc) {
            int c = wv * 8 + cc;
            int ch = h * 64 + c;
            float v0 = Vt[c][m], v1 = Vt[c][m + 1], v2 = Vt[c][m + 2];
            float v3 = Vt[c][m + 3], v4 = Vt[c][m + 4];
            float val = S_s[ch] + v4 * dwv[0] + v3 * dwv[1] + v2 * dwv[2]
                      + v1 * dwv[3] + v0 * dwv[4];
            xr[h][cc] = inp[(size_t)(hb8 * 64 + c) * LL + m0 + m] + val;
        }
    }
    // --- phase 2: split-K channel attention (own x channels + 8 hidden rows) ---
    float acc2[8] = {};
    int cb = __builtin_amdgcn_readfirstlane(wv * 8);
#pragma unroll
    for (int h = 0; h < 4; ++h) {
#pragma unroll
        for (int cc = 0; cc < 8; ++cc) {
            const float* wp = w1T + (h * 64 + cb + cc) * 8;
            float xv = xr[h][cc];
#pragma unroll
            for (int o = 0; o < 8; ++o) acc2[o] += wp[o] * xv;
        }
    }
#pragma unroll
    for (int i = 0; i < 8; ++i) {
        const float* wp = w1T + (256 + cb + i) * 8;
        float xv = hidden[(size_t)(b * 64 + cb + i) * LL + m0 + m];
#pragma unroll
        for (int o = 0; o < 8; ++o) acc2[o] += wp[o] * xv;
    }
#pragma unroll
    for (int o = 0; o < 8; ++o) partial[wv][m][o] = acc2[o];
    __syncthreads();
    float a[8];
#pragma unroll
    for (int o = 0; o < 8; ++o) {
        float v = b1[o];
#pragma unroll
        for (int p = 0; p < 8; ++p) v += partial[p][m][o];
        a[o] = fmaxf(v, 0.f);
    }
    // --- phase 3: gate + write (each wave writes its own 32 channels) ---
#pragma unroll
    for (int h = 0; h < 4; ++h) {
#pragma unroll
        for (int cc = 0; cc < 8; ++cc) {
            int ch = h * 64 + cb + cc;
            const float* wp = w2 + ch * 8;
            float g = b2[ch];
#pragma unroll
            for (int o = 0; o < 8; ++o) g += wp[o] * a[o];
            float gate = 1.f / (1.f + __expf(-g));
            XG[(size_t)(b * 256 + ch) * LL + m0 + m] = xr[h][cc] * gate;
        }
    }
}

// ---------------------------------------------------------------------------
// kConvM: conv1 (256 -> 64) + folded BN + ReLU via bf16 MFMA, split-x 2-pass.
// grid (B, L/64), block 256 (4 waves).
__global__ __launch_bounds__(256) void kConvM(const float* __restrict__ XG,
                                              const ushort_t* __restrict__ wEb,
                                              const float* __restrict__ biasE,
                                              float* __restrict__ Y1) {
    int b = blockIdx.x;
    int l0 = blockIdx.y * 64;
    __shared__ ushort_t xts[2][66][CHP];   // [hi/lo][row=l-l0+1][ch], 70.2KB
    __shared__ float bias_s[64];
    int t = threadIdx.x;
    if (t < 64) bias_s[t] = biasE[t];
    // stage + bf16 split
#pragma unroll 8
    for (int base = 0; base < 66 * 256; base += 256) {
        int idx = base + t;
        int ch = idx / 66, row = idx % 66;
        int l = l0 - 1 + row;
        float x = (l >= 0 && l < LL) ? XG[(size_t)(b * 256 + ch) * LL + l] : 0.f;
        ushort_t hi = f2bf(x);
        ushort_t lo = f2bf(x - bf2f(hi));
        xts[0][row][ch] = hi;
        xts[1][row][ch] = lo;
    }
    __syncthreads();
    int lane = t & 63;
    int wid = t >> 6;
    int wm = wid & 1, wn = wid >> 1;
    int a = lane & 15;       // row (A) / col (B,C) within 16-tile
    int kg = lane >> 4;      // k-group 0..3
    f32x4 acc[2][2] = {};
    union U8 { unsigned u[4]; short8 s; };
#pragma unroll 4
    for (int ks = 0; ks < 24; ++ks) {
        int tap = ks >> 3;
        int ch0 = ((ks & 7) << 5) + (kg << 3);   // (ks%8)*32 + kg*8
        short8 afr[2];
#pragma unroll
        for (int tr = 0; tr < 2; ++tr) {
            const ushort_t* ap = wEb + ((((size_t)(wm * 2 + tr) * 24 + ks) * 64 + lane) << 3);
            afr[tr] = *(const short8*)ap;
        }
#pragma unroll
        for (int tc = 0; tc < 2; ++tc) {
            int row = wn * 32 + tc * 16 + a + tap;
            const ushort_t* xh = &xts[0][row][ch0];
            const ushort_t* xl = &xts[1][row][ch0];
            U8 bh, bl;
#pragma unroll
            for (int q = 0; q < 4; ++q) {
                bh.u[q] = *(const unsigned*)(xh + 2 * q);
                bl.u[q] = *(const unsigned*)(xl + 2 * q);
            }
#pragma unroll
            for (int tr = 0; tr < 2; ++tr) {
                acc[tr][tc] = __builtin_amdgcn_mfma_f32_16x16x32_bf16(
                    afr[tr], bh.s, acc[tr][tc], 0, 0, 0);
                acc[tr][tc] = __builtin_amdgcn_mfma_f32_16x16x32_bf16(
                    afr[tr], bl.s, acc[tr][tc], 0, 0, 0);
            }
        }
    }
#pragma unroll
    for (int tr = 0; tr < 2; ++tr) {
#pragma unroll
        for (int tc = 0; tc < 2; ++tc) {
            int m = wn * 32 + tc * 16 + a;
#pragma unroll
            for (int reg = 0; reg < 4; ++reg) {
                int r = wm * 32 + tr * 16 + kg * 4 + reg;
                float y = acc[tr][tc][reg] + bias_s[r];
                Y1[(size_t)(b * 64 + r) * LL + l0 + m] = fmaxf(y, 0.f);
            }
        }
    }
}

// ---------------------------------------------------------------------------
// kCM2: conv2 (64 -> 64) + folded BN + ReLU via bf16 MFMA, split-y 2-pass.
// grid (B, L/64), block 256 (4 waves). K = 192 tap-major (tap = k>>6, c = k&63).
__global__ __launch_bounds__(256) void kCM2(const float* __restrict__ Y1,
                                            const ushort_t* __restrict__ wFb,
                                            const float* __restrict__ biasF,
                                            float* __restrict__ out) {
    int b = blockIdx.x;
    int l0 = blockIdx.y * 64;
    __shared__ ushort_t yts[2][66][70];   // [hi/lo][row=l-l0+1][c], 18.5KB
    __shared__ float bias_s[64];
    int t = threadIdx.x;
    if (t < 64) bias_s[t] = biasF[t];
#pragma unroll 4
    for (int idx = t; idx < 66 * 64; idx += 256) {
        int c = idx / 66, s = idx % 66;
        int l = l0 - 1 + s;
        float y = (l >= 0 && l < LL) ? Y1[(size_t)(b * 64 + c) * LL + l] : 0.f;
        ushort_t hi = f2bf(y);
        yts[0][s][c] = hi;
        yts[1][s][c] = f2bf(y - bf2f(hi));
    }
    __syncthreads();
    int lane = t & 63;
    int wid = t >> 6;
    int wm = wid & 1, wn = wid >> 1;
    int a = lane & 15;
    int kg = lane >> 4;
    f32x4 acc[2][2] = {};
    union U8 { unsigned u[4]; short8 s; };
#pragma unroll
    for (int ks = 0; ks < 6; ++ks) {
        int tap = ks >> 1;
        int c0 = ((ks & 1) << 5) + (kg << 3);
        short8 afr[2];
#pragma unroll
        for (int tr = 0; tr < 2; ++tr) {
            const ushort_t* ap = wFb + ((((size_t)(wm * 2 + tr) * 6 + ks) * 64 + lane) << 3);
            afr[tr] = *(const short8*)ap;
        }
#pragma unroll
        for (int tc = 0; tc < 2; ++tc) {
            int s = wn * 32 + tc * 16 + a + tap;
            const ushort_t* yh = &yts[0][s][c0];
            const ushort_t* yl = &yts[1][s][c0];
            U8 bh, bl;
#pragma unroll
            for (int q = 0; q < 4; ++q) {
                bh.u[q] = *(const unsigned*)(yh + 2 * q);
                bl.u[q] = *(const unsigned*)(yl + 2 * q);
            }
#pragma unroll
            for (int tr = 0; tr < 2; ++tr) {
                acc[tr][tc] = __builtin_amdgcn_mfma_f32_16x16x32_bf16(
                    afr[tr], bh.s, acc[tr][tc], 0, 0, 0);
                acc[tr][tc] = __builtin_amdgcn_mfma_f32_16x16x32_bf16(
                    afr[tr], bl.s, acc[tr][tc], 0, 0, 0);
            }
        }
    }
#pragma unroll
    for (int tr = 0; tr < 2; ++tr) {
#pragma unroll
        for (int tc = 0; tc < 2; ++tc) {
            int m = wn * 32 + tc * 16 + a;
#pragma unroll
            for (int reg = 0; reg < 4; ++reg) {
                int r = wm * 32 + tr * 16 + kg * 4 + reg;
                float y = acc[tr][tc][reg] + bias_s[r];
                out[(size_t)(b * 64 + r) * LL + l0 + m] = fmaxf(y, 0.f);
            }
        }
    }
}

// ---------------------------------------------------------------------------
extern "C" void kernel_launch(void* const* d_in, const int* in_sizes, int n_in,
                              void* d_out, int out_size, void* d_ws, size_t ws_size,
                              hipStream_t stream) {
    (void)in_sizes; (void)n_in; (void)out_size; (void)ws_size;
    const float* inp    = (const float*)d_in[0];
    const float* hidden = (const float*)d_in[1];
    const float* key_w  = (const float*)d_in[2];
    const float* value_w= (const float*)d_in[3];
    const float* ca_w1  = (const float*)d_in[4];
    const float* ca_b1  = (const float*)d_in[5];
    const float* ca_w2  = (const float*)d_in[6];
    const float* ca_b2  = (const float*)d_in[7];
    const float* pw1    = (const float*)d_in[8];
    const float* bn1_g  = (const float*)d_in[9];
    const float* bn1_b  = (const float*)d_in[10];
    const float* bn1_m  = (const float*)d_in[11];
    const float* bn1_v  = (const float*)d_in[12];
    const float* pw2    = (const float*)d_in[13];
    const float* bn2_g  = (const float*)d_in[14];
    const float* bn2_b  = (const float*)d_in[15];
    const float* bn2_m  = (const float*)d_in[16];
    const float* bn2_v  = (const float*)d_in[17];

    float* ws = (float*)d_ws;
    const size_t KV = (size_t)HH * BB * CC * LL;     // 4,194,304 floats
    float* K = ws;
    float* V = ws + KV;
    float* U = ws + 2 * KV;                          // H*B*L = 65536
    float* W = U + (size_t)HH * BB * LL;             // H*B*L*5 = 327680
    float* Spart = W + (size_t)HH * BB * LL * 5;     // H*B*16*64 = 32768
    float* w1T   = Spart + 32768;                    // 2560
    float* biasE = w1T + 2560;                       // 64
    float* biasF = biasE + 64;                       // 64
    ushort_t* wEb = (ushort_t*)(biasF + 64);         // 49152 bf16 = 24576 floats
    ushort_t* wFb = (ushort_t*)(biasF + 64 + 24576); // 12288 bf16 = 6144 floats
    float* XG = K;   // alias: K dead after kBC
    float* Y1 = V;   // alias: V dead after kD

    kA<<<dim3(33, LL / 64), 256, 0, stream>>>(inp, key_w, value_w, K, V,
                                              pw1, bn1_g, bn1_m, bn1_v, bn1_b,
                                              pw2, bn2_g, bn2_m, bn2_v, bn2_b,
                                              ca_w1, wEb, wFb, biasE, biasF, w1T);
    kBC<<<dim3(HH * BB, LL / 128), 128, 0, stream>>>(K, V, hidden, U, W, Spart);
    kD<<<dim3(BB, LL / 64), 512, 0, stream>>>(inp, hidden, V, U, W, Spart,
                                              w1T, ca_b1, ca_w2, ca_b2, XG);
    kConvM<<<dim3(BB, LL / 64), 256, 0, stream>>>(XG, wEb, biasE, Y1);
    kCM2<<<dim3(BB, LL / 64), 256, 0, stream>>>(Y1, wFb, biasF, (float*)d_out);
}

// Round 8
// 90.347 us; speedup vs baseline: 1.7251x; 1.7251x over previous
//
#include <hip/hip_runtime.h>
#include <hip/hip_bf16.h>
#include <math.h>

// Sizes
#define HH 4
#define BB 8
#define CC 64
#define RR 64
#define LL 2048
#define AA 8
#define HC 256   // H*C
#define EPS 1e-5f
#define CHP 266  // conv1 LDS row pad: 133 dwords/row -> 5-stride bank walk

typedef unsigned short ushort_t;
typedef __attribute__((ext_vector_type(8))) short short8;
typedef __attribute__((ext_vector_type(4))) float f32x4;

static __device__ __forceinline__ ushort_t f2bf(float x) {
    unsigned u = __float_as_uint(x);
    unsigned r = (u + 0x7FFF + ((u >> 16) & 1)) >> 16;
    return (ushort_t)r;
}
static __device__ __forceinline__ float bf2f(ushort_t h) {
    return __uint_as_float(((unsigned)h) << 16);
}

// ---------------------------------------------------------------------------
// Kernel A: fused K/V GEMM (+ weight-prep partition at blockIdx.x==32).
// grid (33, 32), block 256 (4 waves).
__global__ __launch_bounds__(256) void kA(const float* __restrict__ inp,
                                          const float* __restrict__ kw,
                                          const float* __restrict__ vw,
                                          float* __restrict__ K,
                                          float* __restrict__ V,
                                          const float* __restrict__ pw1,
                                          const float* __restrict__ g1,
                                          const float* __restrict__ m1,
                                          const float* __restrict__ v1,
                                          const float* __restrict__ bb1,
                                          const float* __restrict__ pw2,
                                          const float* __restrict__ g2,
                                          const float* __restrict__ m2,
                                          const float* __restrict__ v2,
                                          const float* __restrict__ bb2,
                                          const float* __restrict__ w1ca,
                                          ushort_t* __restrict__ wEb,
                                          ushort_t* __restrict__ wFb,
                                          float* __restrict__ biasE,
                                          float* __restrict__ biasF,
                                          float* __restrict__ w1T) {
    if (blockIdx.x == 32) {
        int tid = blockIdx.y * 256 + threadIdx.x;
        const int stride = 32 * 256;
        // conv1 A-frag bf16 pack: r = rg*16+(lane&15), k = ks*32+(lane>>4)*8+j
        for (int idx = tid; idx < 4 * 24 * 64 * 8; idx += stride) {
            int j = idx & 7, lane = (idx >> 3) & 63, t2 = idx >> 9;
            int ks = t2 % 24, rg = t2 / 24;
            int r = rg * 16 + (lane & 15);
            int k = ks * 32 + (lane >> 4) * 8 + j;
            int tap = k >> 8, ch = k & 255;
            float inv = g1[r] * rsqrtf(v1[r] + EPS);
            wEb[idx] = f2bf(pw1[(r * 256 + ch) * 3 + tap] * inv);
        }
        // conv2 A-frag bf16 pack: K=192, tap = k>>6, c = k&63
        for (int idx = tid; idx < 4 * 6 * 64 * 8; idx += stride) {
            int j = idx & 7, lane = (idx >> 3) & 63, t2 = idx >> 9;
            int ks = t2 % 6, rg = t2 / 6;
            int r = rg * 16 + (lane & 15);
            int k = ks * 32 + (lane >> 4) * 8 + j;
            int tap = k >> 6, c = k & 63;
            float inv = g2[r] * rsqrtf(v2[r] + EPS);
            wFb[idx] = f2bf(pw2[(r * 64 + c) * 3 + tap] * inv);
        }
        for (int idx = tid; idx < 320 * 8; idx += stride)
            w1T[idx] = w1ca[(idx & 7) * 320 + (idx >> 3)];
        if (tid < 64) {
            float inv1 = g1[tid] * rsqrtf(v1[tid] + EPS);
            biasE[tid] = bb1[tid] - m1[tid] * inv1;
            float inv2 = g2[tid] * rsqrtf(v2[tid] + EPS);
            biasF[tid] = bb2[tid] - m2[tid] * inv2;
        }
        return;
    }
    int hb = blockIdx.x;
    int h = hb >> 3;
    int l0 = blockIdx.y * 64;
    __shared__ float in_s[64][64];
    __shared__ float wT[64][128];   // [c][row]; row<64: key, row>=64: value
    int t = threadIdx.x;
    const float* kwh = kw + h * 4096;
    const float* vwh = vw + h * 4096;
    for (int idx = t; idx < 4096; idx += 256) {
        int r = idx >> 6, c = idx & 63;
        wT[c][r] = kwh[idx];
        wT[c][64 + r] = vwh[idx];
    }
    for (int idx = t; idx < 4096; idx += 256) {
        int c = idx >> 6, j = idx & 63;
        in_s[c][j] = inp[(size_t)(hb * 64 + c) * LL + l0 + j];
    }
    __syncthreads();
    int w = t >> 6, lane = t & 63;
    int mg = lane & 15, rg = lane >> 4;
    int rowbase = w * 32 + rg * 8;
    int jx = mg * 4;
    float acc[8][4] = {};
    for (int c = 0; c < 64; ++c) {
        float4 x = *(const float4*)&in_s[c][jx];
        float4 wa = *(const float4*)&wT[c][rowbase];
        float4 wb = *(const float4*)&wT[c][rowbase + 4];
        float wv[8] = {wa.x, wa.y, wa.z, wa.w, wb.x, wb.y, wb.z, wb.w};
        float xv[4] = {x.x, x.y, x.z, x.w};
#pragma unroll
        for (int i = 0; i < 8; ++i)
#pragma unroll
            for (int k = 0; k < 4; ++k)
                acc[i][k] += wv[i] * xv[k];
    }
#pragma unroll
    for (int i = 0; i < 8; ++i) {
        int row = rowbase + i;
        float* dst = (row < 64 ? K : V);
        float4 o = {acc[i][0], acc[i][1], acc[i][2], acc[i][3]};
        *(float4*)&dst[(size_t)(hb * 64 + (row & 63)) * LL + l0 + jx] = o;
    }
}

// ---------------------------------------------------------------------------
// Kernel BC: banded softmax stats (u, w[5]) + S-partials.
// grid (H*B, 32), block 256 (4 waves): 64 l's per block, split-K over 4 r-groups.
__global__ __launch_bounds__(256) void kBC(const float* __restrict__ K,
                                           const float* __restrict__ V,
                                           const float* __restrict__ hidden,
                                           float* __restrict__ U,
                                           float* __restrict__ W,
                                           float* __restrict__ Spart) {
    int hb = blockIdx.x;
    int b = hb & 7;
    int l0 = blockIdx.y * 64;
    __shared__ float k_s[64][68];        // 17.4KB
    __shared__ float partial[4][64][5];  // 5.1KB
    __shared__ float u_s[64];
    __shared__ float red[64][4];         // 1KB
    int t = threadIdx.x;
    const float* Kb = K + (size_t)(hb * 64) * LL;
    for (int idx = t; idx < 64 * 68; idx += 256) {
        int r = idx / 68, jj = idx % 68;
        int m = l0 - 2 + jj;
        k_s[r][jj] = (m >= 0 && m < LL) ? Kb[(size_t)r * LL + m] : 0.f;
    }
    __syncthreads();
    int li = t & 63, rg = t >> 6;
    {
        float acc[5] = {};
        const float* hp = hidden + (size_t)(b * 64 + rg * 16) * LL + l0 + li;
#pragma unroll 4
        for (int i = 0; i < 16; ++i) {
            float h = hp[(size_t)i * LL];
            int r = rg * 16 + i;
            acc[0] += h * k_s[r][li];
            acc[1] += h * k_s[r][li + 1];
            acc[2] += h * k_s[r][li + 2];
            acc[3] += h * k_s[r][li + 3];
            acc[4] += h * k_s[r][li + 4];
        }
#pragma unroll
        for (int d = 0; d < 5; ++d) partial[rg][li][d] = acc[d];
    }
    __syncthreads();
    if (t < 64) {
        int l = l0 + t;
        float raw[5];
        float mx = 0.f;
        int nv = 0;
#pragma unroll
        for (int d = 0; d < 5; ++d) {
            float s = partial[0][t][d] + partial[1][t][d]
                    + partial[2][t][d] + partial[3][t][d];
            int m = l + d - 2;
            bool valid = (m >= 0 && m < LL);
            raw[d] = valid ? s * 0.125f : -1e30f;
            if (valid) { nv++; mx = fmaxf(mx, raw[d]); }
        }
        float e0 = __expf(-mx);
        float Z = (float)(LL - nv) * e0;
        float w[5];
#pragma unroll
        for (int d = 0; d < 5; ++d) {
            float e = (raw[d] > -1e29f) ? __expf(raw[d] - mx) : 0.f;
            w[d] = e;
            Z += e;
        }
        float inv = 1.f / Z;
        float u = e0 * inv;
        U[(size_t)hb * LL + l] = u;
#pragma unroll
        for (int d = 0; d < 5; ++d) W[((size_t)hb * LL + l) * 5 + d] = w[d] * inv;
        u_s[t] = u;
    }
    __syncthreads();
    // S partials: c = t>>2, sub = t&3, 16 strided products
    {
        int c = t >> 2, sub = t & 3;
        const float* Vb = V + (size_t)(hb * 64 + c) * LL + l0;
        float s = 0.f;
#pragma unroll
        for (int i = 0; i < 16; ++i) s += Vb[sub + 4 * i] * u_s[sub + 4 * i];
        red[c][sub] = s;
    }
    __syncthreads();
    if (t < 64)
        Spart[((size_t)hb * 32 + blockIdx.y) * 64 + t]
            = red[t][0] + red[t][1] + red[t][2] + red[t][3];
}

// ---------------------------------------------------------------------------
// Kernel D: val + residual -> x (registers); channel attention -> gate; write XG
// grid (B, L/64), block 512 (8 waves). lane = m; wave wv owns c = wv*8..+8 per head.
__global__ __launch_bounds__(512) void kD(const float* __restrict__ inp,
                                          const float* __restrict__ hidden,
                                          const float* __restrict__ V,
                                          const float* __restrict__ U,
                                          const float* __restrict__ W,
                                          const float* __restrict__ Spart,
                                          const float* __restrict__ w1T,
                                          const float* __restrict__ b1,
                                          const float* __restrict__ w2,
                                          const float* __restrict__ b2,
                                          float* __restrict__ XG) {
    int b = blockIdx.x;
    int m0 = blockIdx.y * 64;
    __shared__ float Vt[64][68];        // 17.4KB
    __shared__ float dw_s[4][68][5];    // 5.4KB
    __shared__ float S2_s[2][256];      // 2KB
    __shared__ float partial[8][64][9]; // 18.4KB
    int t = threadIdx.x;
    int m = t & 63;
    int wv = t >> 6;
    // --- phase 0 staging ---
    for (int idx = t; idx < 4 * 68; idx += 512) {
        int h = idx / 68, j = idx % 68;
        int l = m0 - 2 + j;
        int hb = h * 8 + b;
        if (l >= 0 && l < LL) {
            float u = U[(size_t)hb * LL + l];
            const float* wp = &W[((size_t)hb * LL + l) * 5];
#pragma unroll
            for (int d = 0; d < 5; ++d) dw_s[h][j][d] = wp[d] - u;
        } else {
#pragma unroll
            for (int d = 0; d < 5; ++d) dw_s[h][j][d] = 0.f;
        }
    }
    {
        int qh = t >> 8;        // 0..1
        int ci = t & 255;
        int hb = (ci >> 6) * 8 + b;
        float s = 0.f;
#pragma unroll
        for (int q = 0; q < 16; ++q)
            s += Spart[((size_t)hb * 32 + qh * 16 + q) * 64 + (ci & 63)];
        S2_s[qh][ci] = s;
    }
    // --- phase 1: x = inputs + S + banded correction; x kept in registers ---
    float xr[4][8];
#pragma unroll
    for (int h = 0; h < 4; ++h) {
        __syncthreads();
        int hb8 = h * 8 + b;
        for (int idx = t; idx < 64 * 68; idx += 512) {
            int c = idx / 68, j = idx % 68;
            int l = m0 - 2 + j;
            Vt[c][j] = (l >= 0 && l < LL) ? V[(size_t)(hb8 * 64 + c) * LL + l] : 0.f;
        }
        __syncthreads();
        float dwv[5];
#pragma unroll
        for (int d = 0; d < 5; ++d) dwv[d] = dw_s[h][m + 4 - d][d];
#pragma unroll
        for (int cc = 0; cc < 8; ++cc) {
            int c = wv * 8 + cc;
            int ch = h * 64 + c;
            float v0 = Vt[c][m], v1 = Vt[c][m + 1], v2 = Vt[c][m + 2];
            float v3 = Vt[c][m + 3], v4 = Vt[c][m + 4];
            float val = S2_s[0][ch] + S2_s[1][ch]
                      + v4 * dwv[0] + v3 * dwv[1] + v2 * dwv[2]
                      + v1 * dwv[3] + v0 * dwv[4];
            xr[h][cc] = inp[(size_t)(hb8 * 64 + c) * LL + m0 + m] + val;
        }
    }
    // --- phase 2: split-K channel attention ---
    float acc2[8] = {};
    int cb = __builtin_amdgcn_readfirstlane(wv * 8);
#pragma unroll
    for (int h = 0; h < 4; ++h) {
#pragma unroll
        for (int cc = 0; cc < 8; ++cc) {
            const float* wp = w1T + (h * 64 + cb + cc) * 8;
            float xv = xr[h][cc];
#pragma unroll
            for (int o = 0; o < 8; ++o) acc2[o] += wp[o] * xv;
        }
    }
#pragma unroll
    for (int i = 0; i < 8; ++i) {
        const float* wp = w1T + (256 + cb + i) * 8;
        float xv = hidden[(size_t)(b * 64 + cb + i) * LL + m0 + m];
#pragma unroll
        for (int o = 0; o < 8; ++o) acc2[o] += wp[o] * xv;
    }
#pragma unroll
    for (int o = 0; o < 8; ++o) partial[wv][m][o] = acc2[o];
    __syncthreads();
    float a[8];
#pragma unroll
    for (int o = 0; o < 8; ++o) {
        float v = b1[o];
#pragma unroll
        for (int p = 0; p < 8; ++p) v += partial[p][m][o];
        a[o] = fmaxf(v, 0.f);
    }
    // --- phase 3: gate + write ---
#pragma unroll
    for (int h = 0; h < 4; ++h) {
#pragma unroll
        for (int cc = 0; cc < 8; ++cc) {
            int ch = h * 64 + cb + cc;
            const float* wp = w2 + ch * 8;
            float g = b2[ch];
#pragma unroll
            for (int o = 0; o < 8; ++o) g += wp[o] * a[o];
            float gate = 1.f / (1.f + __expf(-g));
            XG[(size_t)(b * 256 + ch) * LL + m0 + m] = xr[h][cc] * gate;
        }
    }
}

// ---------------------------------------------------------------------------
// kConvM: conv1 (256 -> 64) + folded BN + ReLU via bf16 MFMA, split-x 2-pass.
// grid (B, 64), block 256 (4 waves). l-tile 32 -> 512 blocks, 36KB LDS.
// Wave (wm = wid&1: r-half, wn = wid>>1 in 0..1: m-half of 16).
__global__ __launch_bounds__(256) void kConvM(const float* __restrict__ XG,
                                              const ushort_t* __restrict__ wEb,
                                              const float* __restrict__ biasE,
                                              float* __restrict__ Y1) {
    int b = blockIdx.x;
    int l0 = blockIdx.y * 32;
    __shared__ ushort_t xts[2][34][CHP];   // 35.4KB
    __shared__ float bias_s[64];
    int t = threadIdx.x;
    if (t < 64) bias_s[t] = biasE[t];
    // staging: quads of 4 ch, packed b32 LDS writes
    for (int q = t; q < 34 * 64; q += 256) {
        int row = q % 34;
        int ch0 = (q / 34) * 4;
        int l = l0 - 1 + row;
        bool v = (l >= 0 && l < LL);
        unsigned hp[2], lp[2];
#pragma unroll
        for (int p = 0; p < 2; ++p) {
            unsigned h2 = 0, l2 = 0;
#pragma unroll
            for (int i = 0; i < 2; ++i) {
                int ch = ch0 + p * 2 + i;
                float x = v ? XG[(size_t)(b * 256 + ch) * LL + l] : 0.f;
                ushort_t hi = f2bf(x);
                ushort_t lo = f2bf(x - bf2f(hi));
                h2 |= ((unsigned)hi) << (16 * i);
                l2 |= ((unsigned)lo) << (16 * i);
            }
            hp[p] = h2; lp[p] = l2;
        }
        *(unsigned*)&xts[0][row][ch0] = hp[0];
        *(unsigned*)&xts[0][row][ch0 + 2] = hp[1];
        *(unsigned*)&xts[1][row][ch0] = lp[0];
        *(unsigned*)&xts[1][row][ch0 + 2] = lp[1];
    }
    __syncthreads();
    int lane = t & 63;
    int wid = t >> 6;
    int wm = wid & 1, wn = wid >> 1;   // wn in 0..1
    int a = lane & 15;
    int kg = lane >> 4;
    f32x4 acc[2] = {};
    union U8 { unsigned u[4]; short8 s; };
#pragma unroll 4
    for (int ks = 0; ks < 24; ++ks) {
        int tap = ks >> 3;
        int ch0 = ((ks & 7) << 5) + (kg << 3);
        short8 afr[2];
#pragma unroll
        for (int tr = 0; tr < 2; ++tr) {
            const ushort_t* ap = wEb + ((((size_t)(wm * 2 + tr) * 24 + ks) * 64 + lane) << 3);
            afr[tr] = *(const short8*)ap;
        }
        int row = wn * 16 + a + tap;
        const ushort_t* xh = &xts[0][row][ch0];
        const ushort_t* xl = &xts[1][row][ch0];
        U8 bh, bl;
#pragma unroll
        for (int qq = 0; qq < 4; ++qq) {
            bh.u[qq] = *(const unsigned*)(xh + 2 * qq);
            bl.u[qq] = *(const unsigned*)(xl + 2 * qq);
        }
#pragma unroll
        for (int tr = 0; tr < 2; ++tr) {
            acc[tr] = __builtin_amdgcn_mfma_f32_16x16x32_bf16(afr[tr], bh.s, acc[tr], 0, 0, 0);
            acc[tr] = __builtin_amdgcn_mfma_f32_16x16x32_bf16(afr[tr], bl.s, acc[tr], 0, 0, 0);
        }
    }
#pragma unroll
    for (int tr = 0; tr < 2; ++tr) {
        int m = wn * 16 + a;
#pragma unroll
        for (int reg = 0; reg < 4; ++reg) {
            int r = wm * 32 + tr * 16 + kg * 4 + reg;
            float y = acc[tr][reg] + bias_s[r];
            Y1[(size_t)(b * 64 + r) * LL + l0 + m] = fmaxf(y, 0.f);
        }
    }
}

// ---------------------------------------------------------------------------
// kCM2: conv2 (64 -> 64) + folded BN + ReLU via bf16 MFMA.
// grid (B, 64), block 256 (4 waves), l-tile 32, K=192 tap-major.
__global__ __launch_bounds__(256) void kCM2(const float* __restrict__ Y1,
                                            const ushort_t* __restrict__ wFb,
                                            const float* __restrict__ biasF,
                                            float* __restrict__ out) {
    int b = blockIdx.x;
    int l0 = blockIdx.y * 32;
    __shared__ ushort_t yts[2][34][70];   // 9.5KB
    __shared__ float bias_s[64];
    int t = threadIdx.x;
    if (t < 64) bias_s[t] = biasF[t];
    for (int q = t; q < 34 * 16; q += 256) {
        int row = q % 34;
        int c0 = (q / 34) * 4;
        int l = l0 - 1 + row;
        bool v = (l >= 0 && l < LL);
        unsigned hp[2], lp[2];
#pragma unroll
        for (int p = 0; p < 2; ++p) {
            unsigned h2 = 0, l2 = 0;
#pragma unroll
            for (int i = 0; i < 2; ++i) {
                int c = c0 + p * 2 + i;
                float x = v ? Y1[(size_t)(b * 64 + c) * LL + l] : 0.f;
                ushort_t hi = f2bf(x);
                ushort_t lo = f2bf(x - bf2f(hi));
                h2 |= ((unsigned)hi) << (16 * i);
                l2 |= ((unsigned)lo) << (16 * i);
            }
            hp[p] = h2; lp[p] = l2;
        }
        *(unsigned*)&yts[0][row][c0] = hp[0];
        *(unsigned*)&yts[0][row][c0 + 2] = hp[1];
        *(unsigned*)&yts[1][row][c0] = lp[0];
        *(unsigned*)&yts[1][row][c0 + 2] = lp[1];
    }
    __syncthreads();
    int lane = t & 63;
    int wid = t >> 6;
    int wm = wid & 1, wn = wid >> 1;
    int a = lane & 15;
    int kg = lane >> 4;
    f32x4 acc[2] = {};
    union U8 { unsigned u[4]; short8 s; };
#pragma unroll
    for (int ks = 0; ks < 6; ++ks) {
        int tap = ks >> 1;
        int c0 = ((ks & 1) << 5) + (kg << 3);
        short8 afr[2];
#pragma unroll
        for (int tr = 0; tr < 2; ++tr) {
            const ushort_t* ap = wFb + ((((size_t)(wm * 2 + tr) * 6 + ks) * 64 + lane) << 3);
            afr[tr] = *(const short8*)ap;
        }
        int s = wn * 16 + a + tap;
        const ushort_t* yh = &yts[0][s][c0];
        const ushort_t* yl = &yts[1][s][c0];
        U8 bh, bl;
#pragma unroll
        for (int qq = 0; qq < 4; ++qq) {
            bh.u[qq] = *(const unsigned*)(yh + 2 * qq);
            bl.u[qq] = *(const unsigned*)(yl + 2 * qq);
        }
#pragma unroll
        for (int tr = 0; tr < 2; ++tr) {
            acc[tr] = __builtin_amdgcn_mfma_f32_16x16x32_bf16(afr[tr], bh.s, acc[tr], 0, 0, 0);
            acc[tr] = __builtin_amdgcn_mfma_f32_16x16x32_bf16(afr[tr], bl.s, acc[tr], 0, 0, 0);
        }
    }
#pragma unroll
    for (int tr = 0; tr < 2; ++tr) {
        int m = wn * 16 + a;
#pragma unroll
        for (int reg = 0; reg < 4; ++reg) {
            int r = wm * 32 + tr * 16 + kg * 4 + reg;
            float y = acc[tr][reg] + bias_s[r];
            out[(size_t)(b * 64 + r) * LL + l0 + m] = fmaxf(y, 0.f);
        }
    }
}

// ---------------------------------------------------------------------------
extern "C" void kernel_launch(void* const* d_in, const int* in_sizes, int n_in,
                              void* d_out, int out_size, void* d_ws, size_t ws_size,
                              hipStream_t stream) {
    (void)in_sizes; (void)n_in; (void)out_size; (void)ws_size;
    const float* inp    = (const float*)d_in[0];
    const float* hidden = (const float*)d_in[1];
    const float* key_w  = (const float*)d_in[2];
    const float* value_w= (const float*)d_in[3];
    const float* ca_w1  = (const float*)d_in[4];
    const float* ca_b1  = (const float*)d_in[5];
    const float* ca_w2  = (const float*)d_in[6];
    const float* ca_b2  = (const float*)d_in[7];
    const float* pw1    = (const float*)d_in[8];
    const float* bn1_g  = (const float*)d_in[9];
    const float* bn1_b  = (const float*)d_in[10];
    const float* bn1_m  = (const float*)d_in[11];
    const float* bn1_v  = (const float*)d_in[12];
    const float* pw2    = (const float*)d_in[13];
    const float* bn2_g  = (const float*)d_in[14];
    const float* bn2_b  = (const float*)d_in[15];
    const float* bn2_m  = (const float*)d_in[16];
    const float* bn2_v  = (const float*)d_in[17];

    float* ws = (float*)d_ws;
    const size_t KV = (size_t)HH * BB * CC * LL;     // 4,194,304 floats
    float* K = ws;
    float* V = ws + KV;
    float* U = ws + 2 * KV;                          // 65536
    float* W = U + (size_t)HH * BB * LL;             // 327680
    float* Spart = W + (size_t)HH * BB * LL * 5;     // H*B*32*64 = 65536
    float* w1T   = Spart + 65536;                    // 2560
    float* biasE = w1T + 2560;                       // 64
    float* biasF = biasE + 64;                       // 64
    ushort_t* wEb = (ushort_t*)(biasF + 64);         // 49152 bf16 = 24576 floats
    ushort_t* wFb = (ushort_t*)(biasF + 64 + 24576); // 12288 bf16 = 6144 floats
    float* XG = K;   // alias: K dead after kBC
    float* Y1 = V;   // alias: V dead after kD

    kA<<<dim3(33, LL / 64), 256, 0, stream>>>(inp, key_w, value_w, K, V,
                                              pw1, bn1_g, bn1_m, bn1_v, bn1_b,
                                              pw2, bn2_g, bn2_m, bn2_v, bn2_b,
                                              ca_w1, wEb, wFb, biasE, biasF, w1T);
    kBC<<<dim3(HH * BB, 32), 256, 0, stream>>>(K, V, hidden, U, W, Spart);
    kD<<<dim3(BB, LL / 64), 512, 0, stream>>>(inp, hidden, V, U, W, Spart,
                                              w1T, ca_b1, ca_w2, ca_b2, XG);
    kConvM<<<dim3(BB, 64), 256, 0, stream>>>(XG, wEb, biasE, Y1);
    kCM2<<<dim3(BB, 64), 256, 0, stream>>>(Y1, wFb, biasF, (float*)d_out);
}

// Round 9
// 83.916 us; speedup vs baseline: 1.8573x; 1.0766x over previous
//
#include <hip/hip_runtime.h>
#include <hip/hip_bf16.h>
#include <math.h>

// Sizes
#define HH 4
#define BB 8
#define CC 64
#define RR 64
#define LL 2048
#define AA 8
#define HC 256   // H*C
#define EPS 1e-5f
#define CHP 266  // conv1 LDS row pad: 133 dwords/row -> 5-stride bank walk
#define WTP 132  // kA wT row pad: 132 ≡ 4 (mod 32) -> 8-way staging, clean reads

typedef unsigned short ushort_t;
typedef __attribute__((ext_vector_type(8))) short short8;
typedef __attribute__((ext_vector_type(4))) float f32x4;

static __device__ __forceinline__ ushort_t f2bf(float x) {
    unsigned u = __float_as_uint(x);
    unsigned r = (u + 0x7FFF + ((u >> 16) & 1)) >> 16;
    return (ushort_t)r;
}
static __device__ __forceinline__ float bf2f(ushort_t h) {
    return __uint_as_float(((unsigned)h) << 16);
}

// ---------------------------------------------------------------------------
// Kernel A: fused K/V GEMM (+ weight-prep partition at blockIdx.x==32).
// grid (33, 32), block 256 (4 waves).
__global__ __launch_bounds__(256) void kA(const float* __restrict__ inp,
                                          const float* __restrict__ kw,
                                          const float* __restrict__ vw,
                                          float* __restrict__ K,
                                          float* __restrict__ V,
                                          const float* __restrict__ pw1,
                                          const float* __restrict__ g1,
                                          const float* __restrict__ m1,
                                          const float* __restrict__ v1,
                                          const float* __restrict__ bb1,
                                          const float* __restrict__ pw2,
                                          const float* __restrict__ g2,
                                          const float* __restrict__ m2,
                                          const float* __restrict__ v2,
                                          const float* __restrict__ bb2,
                                          const float* __restrict__ w1ca,
                                          ushort_t* __restrict__ wEb,
                                          ushort_t* __restrict__ wFb,
                                          float* __restrict__ biasE,
                                          float* __restrict__ biasF,
                                          float* __restrict__ w1T) {
    if (blockIdx.x == 32) {
        int tid = blockIdx.y * 256 + threadIdx.x;
        const int stride = 32 * 256;
        // conv1 A-frag bf16 pack: r = rg*16+(lane&15), k = ks*32+(lane>>4)*8+j
        for (int idx = tid; idx < 4 * 24 * 64 * 8; idx += stride) {
            int j = idx & 7, lane = (idx >> 3) & 63, t2 = idx >> 9;
            int ks = t2 % 24, rg = t2 / 24;
            int r = rg * 16 + (lane & 15);
            int k = ks * 32 + (lane >> 4) * 8 + j;
            int tap = k >> 8, ch = k & 255;
            float inv = g1[r] * rsqrtf(v1[r] + EPS);
            wEb[idx] = f2bf(pw1[(r * 256 + ch) * 3 + tap] * inv);
        }
        // conv2 A-frag bf16 pack: K=192, tap = k>>6, c = k&63
        for (int idx = tid; idx < 4 * 6 * 64 * 8; idx += stride) {
            int j = idx & 7, lane = (idx >> 3) & 63, t2 = idx >> 9;
            int ks = t2 % 6, rg = t2 / 6;
            int r = rg * 16 + (lane & 15);
            int k = ks * 32 + (lane >> 4) * 8 + j;
            int tap = k >> 6, c = k & 63;
            float inv = g2[r] * rsqrtf(v2[r] + EPS);
            wFb[idx] = f2bf(pw2[(r * 64 + c) * 3 + tap] * inv);
        }
        for (int idx = tid; idx < 320 * 8; idx += stride)
            w1T[idx] = w1ca[(idx & 7) * 320 + (idx >> 3)];
        if (tid < 64) {
            float inv1 = g1[tid] * rsqrtf(v1[tid] + EPS);
            biasE[tid] = bb1[tid] - m1[tid] * inv1;
            float inv2 = g2[tid] * rsqrtf(v2[tid] + EPS);
            biasF[tid] = bb2[tid] - m2[tid] * inv2;
        }
        return;
    }
    int hb = blockIdx.x;
    int h = hb >> 3;
    int l0 = blockIdx.y * 64;
    __shared__ float in_s[64][64];
    __shared__ float wT[64][WTP];   // [c][row]; row<64: key, row>=64: value
    int t = threadIdx.x;
    const float* kwh = kw + h * 4096;
    const float* vwh = vw + h * 4096;
    for (int idx = t; idx < 4096; idx += 256) {
        int r = idx >> 6, c = idx & 63;
        wT[c][r] = kwh[idx];
        wT[c][64 + r] = vwh[idx];
    }
    for (int idx = t; idx < 4096; idx += 256) {
        int c = idx >> 6, j = idx & 63;
        in_s[c][j] = inp[(size_t)(hb * 64 + c) * LL + l0 + j];
    }
    __syncthreads();
    int w = t >> 6, lane = t & 63;
    int mg = lane & 15, rg = lane >> 4;
    int rowbase = w * 32 + rg * 8;
    int jx = mg * 4;
    float acc[8][4] = {};
    for (int c = 0; c < 64; ++c) {
        float4 x = *(const float4*)&in_s[c][jx];
        float4 wa = *(const float4*)&wT[c][rowbase];
        float4 wb = *(const float4*)&wT[c][rowbase + 4];
        float wv[8] = {wa.x, wa.y, wa.z, wa.w, wb.x, wb.y, wb.z, wb.w};
        float xv[4] = {x.x, x.y, x.z, x.w};
#pragma unroll
        for (int i = 0; i < 8; ++i)
#pragma unroll
            for (int k = 0; k < 4; ++k)
                acc[i][k] += wv[i] * xv[k];
    }
#pragma unroll
    for (int i = 0; i < 8; ++i) {
        int row = rowbase + i;
        float* dst = (row < 64 ? K : V);
        float4 o = {acc[i][0], acc[i][1], acc[i][2], acc[i][3]};
        *(float4*)&dst[(size_t)(hb * 64 + (row & 63)) * LL + l0 + jx] = o;
    }
}

// ---------------------------------------------------------------------------
// Kernel BC: banded softmax stats (u, w[5]) + S-partials.
// grid (H*B, 32), block 256 (4 waves): 64 l's per block, split-K over 4 r-groups.
__global__ __launch_bounds__(256) void kBC(const float* __restrict__ K,
                                           const float* __restrict__ V,
                                           const float* __restrict__ hidden,
                                           float* __restrict__ U,
                                           float* __restrict__ W,
                                           float* __restrict__ Spart) {
    int hb = blockIdx.x;
    int b = hb & 7;
    int l0 = blockIdx.y * 64;
    __shared__ float k_s[64][68];        // 17.4KB
    __shared__ float partial[4][64][5];  // 5.1KB
    __shared__ float u_s[64];
    __shared__ float red[64][4];         // 1KB
    int t = threadIdx.x;
    const float* Kb = K + (size_t)(hb * 64) * LL;
    for (int idx = t; idx < 64 * 68; idx += 256) {
        int r = idx / 68, jj = idx % 68;
        int m = l0 - 2 + jj;
        k_s[r][jj] = (m >= 0 && m < LL) ? Kb[(size_t)r * LL + m] : 0.f;
    }
    __syncthreads();
    int li = t & 63, rg = t >> 6;
    {
        float acc[5] = {};
        const float* hp = hidden + (size_t)(b * 64 + rg * 16) * LL + l0 + li;
#pragma unroll 4
        for (int i = 0; i < 16; ++i) {
            float h = hp[(size_t)i * LL];
            int r = rg * 16 + i;
            acc[0] += h * k_s[r][li];
            acc[1] += h * k_s[r][li + 1];
            acc[2] += h * k_s[r][li + 2];
            acc[3] += h * k_s[r][li + 3];
            acc[4] += h * k_s[r][li + 4];
        }
#pragma unroll
        for (int d = 0; d < 5; ++d) partial[rg][li][d] = acc[d];
    }
    __syncthreads();
    if (t < 64) {
        int l = l0 + t;
        float raw[5];
        float mx = 0.f;
        int nv = 0;
#pragma unroll
        for (int d = 0; d < 5; ++d) {
            float s = partial[0][t][d] + partial[1][t][d]
                    + partial[2][t][d] + partial[3][t][d];
            int m = l + d - 2;
            bool valid = (m >= 0 && m < LL);
            raw[d] = valid ? s * 0.125f : -1e30f;
            if (valid) { nv++; mx = fmaxf(mx, raw[d]); }
        }
        float e0 = __expf(-mx);
        float Z = (float)(LL - nv) * e0;
        float w[5];
#pragma unroll
        for (int d = 0; d < 5; ++d) {
            float e = (raw[d] > -1e29f) ? __expf(raw[d] - mx) : 0.f;
            w[d] = e;
            Z += e;
        }
        float inv = 1.f / Z;
        float u = e0 * inv;
        U[(size_t)hb * LL + l] = u;
#pragma unroll
        for (int d = 0; d < 5; ++d) W[((size_t)hb * LL + l) * 5 + d] = w[d] * inv;
        u_s[t] = u;
    }
    __syncthreads();
    // S partials: c = t>>2, sub = t&3, 16 strided products
    {
        int c = t >> 2, sub = t & 3;
        const float* Vb = V + (size_t)(hb * 64 + c) * LL + l0;
        float s = 0.f;
#pragma unroll
        for (int i = 0; i < 16; ++i) s += Vb[sub + 4 * i] * u_s[sub + 4 * i];
        red[c][sub] = s;
    }
    __syncthreads();
    if (t < 64)
        Spart[((size_t)hb * 32 + blockIdx.y) * 64 + t]
            = red[t][0] + red[t][1] + red[t][2] + red[t][3];
}

// ---------------------------------------------------------------------------
// Kernel D: val + residual -> x (registers); channel attention -> gate; write XG
// grid (B, L/64), block 512 (8 waves). lane = m; wave wv owns c = wv*8..+8 per head.
__global__ __launch_bounds__(512) void kD(const float* __restrict__ inp,
                                          const float* __restrict__ hidden,
                                          const float* __restrict__ V,
                                          const float* __restrict__ U,
                                          const float* __restrict__ W,
                                          const float* __restrict__ Spart,
                                          const float* __restrict__ w1T,
                                          const float* __restrict__ b1,
                                          const float* __restrict__ w2,
                                          const float* __restrict__ b2,
                                          float* __restrict__ XG) {
    int b = blockIdx.x;
    int m0 = blockIdx.y * 64;
    __shared__ float Vt[64][68];        // 17.4KB
    __shared__ float dw_s[4][68][5];    // 5.4KB
    __shared__ float S2_s[2][256];      // 2KB
    __shared__ float partial[8][64][9]; // 18.4KB
    int t = threadIdx.x;
    int m = t & 63;
    int wv = t >> 6;
    // --- phase 0 staging ---
    for (int idx = t; idx < 4 * 68; idx += 512) {
        int h = idx / 68, j = idx % 68;
        int l = m0 - 2 + j;
        int hb = h * 8 + b;
        if (l >= 0 && l < LL) {
            float u = U[(size_t)hb * LL + l];
            const float* wp = &W[((size_t)hb * LL + l) * 5];
#pragma unroll
            for (int d = 0; d < 5; ++d) dw_s[h][j][d] = wp[d] - u;
        } else {
#pragma unroll
            for (int d = 0; d < 5; ++d) dw_s[h][j][d] = 0.f;
        }
    }
    {
        int qh = t >> 8;        // 0..1
        int ci = t & 255;
        int hb = (ci >> 6) * 8 + b;
        float s = 0.f;
#pragma unroll
        for (int q = 0; q < 16; ++q)
            s += Spart[((size_t)hb * 32 + qh * 16 + q) * 64 + (ci & 63)];
        S2_s[qh][ci] = s;
    }
    // --- phase 1: x = inputs + S + banded correction; x kept in registers ---
    float xr[4][8];
#pragma unroll
    for (int h = 0; h < 4; ++h) {
        __syncthreads();
        int hb8 = h * 8 + b;
        for (int idx = t; idx < 64 * 68; idx += 512) {
            int c = idx / 68, j = idx % 68;
            int l = m0 - 2 + j;
            Vt[c][j] = (l >= 0 && l < LL) ? V[(size_t)(hb8 * 64 + c) * LL + l] : 0.f;
        }
        __syncthreads();
        float dwv[5];
#pragma unroll
        for (int d = 0; d < 5; ++d) dwv[d] = dw_s[h][m + 4 - d][d];
#pragma unroll
        for (int cc = 0; cc < 8; ++cc) {
            int c = wv * 8 + cc;
            int ch = h * 64 + c;
            float v0 = Vt[c][m], v1 = Vt[c][m + 1], v2 = Vt[c][m + 2];
            float v3 = Vt[c][m + 3], v4 = Vt[c][m + 4];
            float val = S2_s[0][ch] + S2_s[1][ch]
                      + v4 * dwv[0] + v3 * dwv[1] + v2 * dwv[2]
                      + v1 * dwv[3] + v0 * dwv[4];
            xr[h][cc] = inp[(size_t)(hb8 * 64 + c) * LL + m0 + m] + val;
        }
    }
    // --- phase 2: split-K channel attention ---
    float acc2[8] = {};
    int cb = __builtin_amdgcn_readfirstlane(wv * 8);
#pragma unroll
    for (int h = 0; h < 4; ++h) {
#pragma unroll
        for (int cc = 0; cc < 8; ++cc) {
            const float* wp = w1T + (h * 64 + cb + cc) * 8;
            float xv = xr[h][cc];
#pragma unroll
            for (int o = 0; o < 8; ++o) acc2[o] += wp[o] * xv;
        }
    }
#pragma unroll
    for (int i = 0; i < 8; ++i) {
        const float* wp = w1T + (256 + cb + i) * 8;
        float xv = hidden[(size_t)(b * 64 + cb + i) * LL + m0 + m];
#pragma unroll
        for (int o = 0; o < 8; ++o) acc2[o] += wp[o] * xv;
    }
#pragma unroll
    for (int o = 0; o < 8; ++o) partial[wv][m][o] = acc2[o];
    __syncthreads();
    float a[8];
#pragma unroll
    for (int o = 0; o < 8; ++o) {
        float v = b1[o];
#pragma unroll
        for (int p = 0; p < 8; ++p) v += partial[p][m][o];
        a[o] = fmaxf(v, 0.f);
    }
    // --- phase 3: gate + write ---
#pragma unroll
    for (int h = 0; h < 4; ++h) {
#pragma unroll
        for (int cc = 0; cc < 8; ++cc) {
            int ch = h * 64 + cb + cc;
            const float* wp = w2 + ch * 8;
            float g = b2[ch];
#pragma unroll
            for (int o = 0; o < 8; ++o) g += wp[o] * a[o];
            float gate = 1.f / (1.f + __expf(-g));
            XG[(size_t)(b * 256 + ch) * LL + m0 + m] = xr[h][cc] * gate;
        }
    }
}

// ---------------------------------------------------------------------------
// kConvM: conv1 (256 -> 64) + folded BN + ReLU via bf16 MFMA, split-x 2-pass.
// grid (B, 64), block 256 (4 waves). l-tile 32 -> 512 blocks, 36KB LDS.
__global__ __launch_bounds__(256) void kConvM(const float* __restrict__ XG,
                                              const ushort_t* __restrict__ wEb,
                                              const float* __restrict__ biasE,
                                              float* __restrict__ Y1) {
    int b = blockIdx.x;
    int l0 = blockIdx.y * 32;
    __shared__ ushort_t xts[2][34][CHP];   // 35.4KB
    __shared__ float bias_s[64];
    int t = threadIdx.x;
    if (t < 64) bias_s[t] = biasE[t];
    // staging: quads of 4 ch, packed b32 LDS writes
    for (int q = t; q < 34 * 64; q += 256) {
        int row = q % 34;
        int ch0 = (q / 34) * 4;
        int l = l0 - 1 + row;
        bool v = (l >= 0 && l < LL);
        unsigned hp[2], lp[2];
#pragma unroll
        for (int p = 0; p < 2; ++p) {
            unsigned h2 = 0, l2 = 0;
#pragma unroll
            for (int i = 0; i < 2; ++i) {
                int ch = ch0 + p * 2 + i;
                float x = v ? XG[(size_t)(b * 256 + ch) * LL + l] : 0.f;
                ushort_t hi = f2bf(x);
                ushort_t lo = f2bf(x - bf2f(hi));
                h2 |= ((unsigned)hi) << (16 * i);
                l2 |= ((unsigned)lo) << (16 * i);
            }
            hp[p] = h2; lp[p] = l2;
        }
        *(unsigned*)&xts[0][row][ch0] = hp[0];
        *(unsigned*)&xts[0][row][ch0 + 2] = hp[1];
        *(unsigned*)&xts[1][row][ch0] = lp[0];
        *(unsigned*)&xts[1][row][ch0 + 2] = lp[1];
    }
    __syncthreads();
    int lane = t & 63;
    int wid = t >> 6;
    int wm = wid & 1, wn = wid >> 1;   // wn in 0..1
    int a = lane & 15;
    int kg = lane >> 4;
    f32x4 acc[2] = {};
    union U8 { unsigned u[4]; short8 s; };
#pragma unroll 4
    for (int ks = 0; ks < 24; ++ks) {
        int tap = ks >> 3;
        int ch0 = ((ks & 7) << 5) + (kg << 3);
        short8 afr[2];
#pragma unroll
        for (int tr = 0; tr < 2; ++tr) {
            const ushort_t* ap = wEb + ((((size_t)(wm * 2 + tr) * 24 + ks) * 64 + lane) << 3);
            afr[tr] = *(const short8*)ap;
        }
        int row = wn * 16 + a + tap;
        const ushort_t* xh = &xts[0][row][ch0];
        const ushort_t* xl = &xts[1][row][ch0];
        U8 bh, bl;
#pragma unroll
        for (int qq = 0; qq < 4; ++qq) {
            bh.u[qq] = *(const unsigned*)(xh + 2 * qq);
            bl.u[qq] = *(const unsigned*)(xl + 2 * qq);
        }
#pragma unroll
        for (int tr = 0; tr < 2; ++tr) {
            acc[tr] = __builtin_amdgcn_mfma_f32_16x16x32_bf16(afr[tr], bh.s, acc[tr], 0, 0, 0);
            acc[tr] = __builtin_amdgcn_mfma_f32_16x16x32_bf16(afr[tr], bl.s, acc[tr], 0, 0, 0);
        }
    }
#pragma unroll
    for (int tr = 0; tr < 2; ++tr) {
        int m = wn * 16 + a;
#pragma unroll
        for (int reg = 0; reg < 4; ++reg) {
            int r = wm * 32 + tr * 16 + kg * 4 + reg;
            float y = acc[tr][reg] + bias_s[r];
            Y1[(size_t)(b * 64 + r) * LL + l0 + m] = fmaxf(y, 0.f);
        }
    }
}

// ---------------------------------------------------------------------------
// kCM2: conv2 (64 -> 64) + folded BN + ReLU via bf16 MFMA.
// grid (B, 64), block 256 (4 waves), l-tile 32, K=192 tap-major.
__global__ __launch_bounds__(256) void kCM2(const float* __restrict__ Y1,
                                            const ushort_t* __restrict__ wFb,
                                            const float* __restrict__ biasF,
                                            float* __restrict__ out) {
    int b = blockIdx.x;
    int l0 = blockIdx.y * 32;
    __shared__ ushort_t yts[2][34][70];   // 9.5KB
    __shared__ float bias_s[64];
    int t = threadIdx.x;
    if (t < 64) bias_s[t] = biasF[t];
    for (int q = t; q < 34 * 16; q += 256) {
        int row = q % 34;
        int c0 = (q / 34) * 4;
        int l = l0 - 1 + row;
        bool v = (l >= 0 && l < LL);
        unsigned hp[2], lp[2];
#pragma unroll
        for (int p = 0; p < 2; ++p) {
            unsigned h2 = 0, l2 = 0;
#pragma unroll
            for (int i = 0; i < 2; ++i) {
                int c = c0 + p * 2 + i;
                float x = v ? Y1[(size_t)(b * 64 + c) * LL + l] : 0.f;
                ushort_t hi = f2bf(x);
                ushort_t lo = f2bf(x - bf2f(hi));
                h2 |= ((unsigned)hi) << (16 * i);
                l2 |= ((unsigned)lo) << (16 * i);
            }
            hp[p] = h2; lp[p] = l2;
        }
        *(unsigned*)&yts[0][row][c0] = hp[0];
        *(unsigned*)&yts[0][row][c0 + 2] = hp[1];
        *(unsigned*)&yts[1][row][c0] = lp[0];
        *(unsigned*)&yts[1][row][c0 + 2] = lp[1];
    }
    __syncthreads();
    int lane = t & 63;
    int wid = t >> 6;
    int wm = wid & 1, wn = wid >> 1;
    int a = lane & 15;
    int kg = lane >> 4;
    f32x4 acc[2] = {};
    union U8 { unsigned u[4]; short8 s; };
#pragma unroll
    for (int ks = 0; ks < 6; ++ks) {
        int tap = ks >> 1;
        int c0 = ((ks & 1) << 5) + (kg << 3);
        short8 afr[2];
#pragma unroll
        for (int tr = 0; tr < 2; ++tr) {
            const ushort_t* ap = wFb + ((((size_t)(wm * 2 + tr) * 6 + ks) * 64 + lane) << 3);
            afr[tr] = *(const short8*)ap;
        }
        int s = wn * 16 + a + tap;
        const ushort_t* yh = &yts[0][s][c0];
        const ushort_t* yl = &yts[1][s][c0];
        U8 bh, bl;
#pragma unroll
        for (int qq = 0; qq < 4; ++qq) {
            bh.u[qq] = *(const unsigned*)(yh + 2 * qq);
            bl.u[qq] = *(const unsigned*)(yl + 2 * qq);
        }
#pragma unroll
        for (int tr = 0; tr < 2; ++tr) {
            acc[tr] = __builtin_amdgcn_mfma_f32_16x16x32_bf16(afr[tr], bh.s, acc[tr], 0, 0, 0);
            acc[tr] = __builtin_amdgcn_mfma_f32_16x16x32_bf16(afr[tr], bl.s, acc[tr], 0, 0, 0);
        }
    }
#pragma unroll
    for (int tr = 0; tr < 2; ++tr) {
        int m = wn * 16 + a;
#pragma unroll
        for (int reg = 0; reg < 4; ++reg) {
            int r = wm * 32 + tr * 16 + kg * 4 + reg;
            float y = acc[tr][reg] + bias_s[r];
            out[(size_t)(b * 64 + r) * LL + l0 + m] = fmaxf(y, 0.f);
        }
    }
}

// ---------------------------------------------------------------------------
extern "C" void kernel_launch(void* const* d_in, const int* in_sizes, int n_in,
                              void* d_out, int out_size, void* d_ws, size_t ws_size,
                              hipStream_t stream) {
    (void)in_sizes; (void)n_in; (void)out_size; (void)ws_size;
    const float* inp    = (const float*)d_in[0];
    const float* hidden = (const float*)d_in[1];
    const float* key_w  = (const float*)d_in[2];
    const float* value_w= (const float*)d_in[3];
    const float* ca_w1  = (const float*)d_in[4];
    const float* ca_b1  = (const float*)d_in[5];
    const float* ca_w2  = (const float*)d_in[6];
    const float* ca_b2  = (const float*)d_in[7];
    const float* pw1    = (const float*)d_in[8];
    const float* bn1_g  = (const float*)d_in[9];
    const float* bn1_b  = (const float*)d_in[10];
    const float* bn1_m  = (const float*)d_in[11];
    const float* bn1_v  = (const float*)d_in[12];
    const float* pw2    = (const float*)d_in[13];
    const float* bn2_g  = (const float*)d_in[14];
    const float* bn2_b  = (const float*)d_in[15];
    const float* bn2_m  = (const float*)d_in[16];
    const float* bn2_v  = (const float*)d_in[17];

    float* ws = (float*)d_ws;
    const size_t KV = (size_t)HH * BB * CC * LL;     // 4,194,304 floats
    float* K = ws;
    float* V = ws + KV;
    float* U = ws + 2 * KV;                          // 65536
    float* W = U + (size_t)HH * BB * LL;             // 327680
    float* Spart = W + (size_t)HH * BB * LL * 5;     // H*B*32*64 = 65536
    float* w1T   = Spart + 65536;                    // 2560
    float* biasE = w1T + 2560;                       // 64
    float* biasF = biasE + 64;                       // 64
    ushort_t* wEb = (ushort_t*)(biasF + 64);         // 49152 bf16 = 24576 floats
    ushort_t* wFb = (ushort_t*)(biasF + 64 + 24576); // 12288 bf16 = 6144 floats
    float* XG = K;   // alias: K dead after kBC
    float* Y1 = V;   // alias: V dead after kD

    kA<<<dim3(33, LL / 64), 256, 0, stream>>>(inp, key_w, value_w, K, V,
                                              pw1, bn1_g, bn1_m, bn1_v, bn1_b,
                                              pw2, bn2_g, bn2_m, bn2_v, bn2_b,
                                              ca_w1, wEb, wFb, biasE, biasF, w1T);
    kBC<<<dim3(HH * BB, 32), 256, 0, stream>>>(K, V, hidden, U, W, Spart);
    kD<<<dim3(BB, LL / 64), 512, 0, stream>>>(inp, hidden, V, U, W, Spart,
                                              w1T, ca_b1, ca_w2, ca_b2, XG);
    kConvM<<<dim3(BB, 64), 256, 0, stream>>>(XG, wEb, biasE, Y1);
    kCM2<<<dim3(BB, 64), 256, 0, stream>>>(Y1, wFb, biasF, (float*)d_out);
}